// Round 1
// 1787.823 us; speedup vs baseline: 1.0092x; 1.0092x over previous
//
#include <hip/hip_runtime.h>
#include <hip/hip_bf16.h>

#define BATCHN 64
#define SEQ    2048
#define HID    64
#define NF     32
#define DIN    96      // NF + HID
#define G7     448     // 7 * HID
#define CH     33      // time + 32 marks
#define REC_T  256     // 4 waves

using bf16 = __hip_bfloat16;

__device__ __forceinline__ float b2f(bf16 v) { return __bfloat162float(v); }

// Inputs are float32 (verified R4/R5). flag==1 -> fp32, flag==0 -> bf16.
__device__ __forceinline__ float ldin(const void* p, size_t i, bool f32) {
    return f32 ? ((const float*)p)[i] : b2f(((const bf16*)p)[i]);
}

// Fast math: v_exp/v_rcp based, saturation-safe, NaN-free (verified R5).
__device__ __forceinline__ float fast_rcp(float x) { return __builtin_amdgcn_rcpf(x); }
__device__ __forceinline__ float sigmoid_f(float x) {
    return fast_rcp(1.0f + __expf(-x));
}
__device__ __forceinline__ float tanh_f(float x) {
    float e = __expf(2.0f * x);
    return 1.0f - 2.0f * fast_rcp(e + 1.0f);
}
__device__ __forceinline__ float softplus_f(float x) {
    float e = __expf(-fabsf(x));
    return fmaxf(x, 0.0f) + __logf(1.0f + e);
}

// Broadcast lane k of v to all lanes (uniform k -> v_readlane -> SGPR operand).
__device__ __forceinline__ float rl(float v, int lane) {
    return __uint_as_float(__builtin_amdgcn_readlane(__float_as_uint(v), lane));
}

__global__ void detect_dtype(const void* batch, int* flag) {
    if (threadIdx.x != 0 || blockIdx.x != 0) return;
    const float* bf = (const float*)batch;
    bool mono = true;
    float prev = bf[0];
    if (!(prev > 0.004f && prev < 1.3f)) mono = false;
    for (int t = 1; t < 16 && mono; ++t) {
        float cur = bf[(size_t)t * CH];
        if (!(cur > prev && (cur - prev) < 1.3f)) mono = false;
        prev = cur;
    }
    *flag = mono ? 1 : 0;
}

// ---------------- x-projection GEMM (fully parallel) ----------------
__global__ __launch_bounds__(G7) void xproj_gemm(
    const void* __restrict__ batch, const void* __restrict__ W_rec,
    const void* __restrict__ b_rec, float* __restrict__ xz,
    const int* __restrict__ flag)
{
    const bool f32 = *flag != 0;
    const int tid = threadIdx.x;
    const size_t base = (size_t)blockIdx.x * 64;   // 64 rows per block

    float wx[NF];
    if (f32) {
        const float* W = (const float*)W_rec;
#pragma unroll
        for (int k = 0; k < NF; ++k) wx[k] = W[(size_t)k * G7 + tid];
    } else {
        const bf16* W = (const bf16*)W_rec;
#pragma unroll
        for (int k = 0; k < NF; ++k) wx[k] = b2f(W[(size_t)k * G7 + tid]);
    }
    const float bias = ldin(b_rec, tid, f32);

    __shared__ __align__(16) float s_x[64][NF];    // 8 KB
    for (int i = tid; i < 64 * NF; i += G7) {
        const int r = i >> 5, k = i & 31;
        s_x[r][k] = ldin(batch, (base + r) * CH + 1 + k, f32);
    }
    __syncthreads();

    for (int r = 0; r < 64; ++r) {
        const float4* xv = (const float4*)s_x[r];
        float a0 = 0.f, a1 = 0.f, a2 = 0.f, a3 = 0.f;
#pragma unroll
        for (int k4 = 0; k4 < NF / 4; ++k4) {
            float4 v = xv[k4];
            a0 = fmaf(v.x, wx[4 * k4 + 0], a0);
            a1 = fmaf(v.y, wx[4 * k4 + 1], a1);
            a2 = fmaf(v.z, wx[4 * k4 + 2], a2);
            a3 = fmaf(v.w, wx[4 * k4 + 3], a3);
        }
        xz[(base + r) * G7 + tid] = bias + ((a0 + a1) + (a2 + a3));
    }
}

// ---------------- recurrent kernel: 4-wave, weights-in-registers ----------
// Wave w, lane j owns gate columns c0 = w*64+j (gates 0..3) and
// c1 = (w+4)*64+j (gates 4..6; wave 3 duplicates c0). float2 wh[64] = 128
// VGPRs of weights, register-resident via __launch_bounds__(256,1)
// (1 wave/SIMD -> 512-VGPR budget, no spill). Phase C is replicated in all
// waves so h is a per-lane REGISTER; Phase B broadcasts it with v_readlane
// (no s_h LDS round-trip). Barrier is raw lgkmcnt(0)+s_barrier: no vmcnt(0)
// store drain on the critical path. s_act parity double-buffer as before.
__global__ __launch_bounds__(REC_T, 1) void ctlstm_rec_xz4(
    const void* __restrict__ batch, const void* __restrict__ W_rec,
    const float* __restrict__ xz, float* __restrict__ out,
    float* __restrict__ h_ws, const int* __restrict__ flag)
{
    const bool f32 = *flag != 0;
    const int tid  = threadIdx.x;
    const int wave = tid >> 6;      // gate g0 = wave, g1 = wave+4
    const int lane = tid & 63;      // hidden unit j
    const int b    = blockIdx.x;
    const size_t bT = (size_t)b * SEQ;

    float* out_o  = out;
    float* out_c  = out + (size_t)BATCHN * SEQ * HID;
    float* out_cb = out + 2 * (size_t)BATCHN * SEQ * HID;
    float* out_dl = out + 3 * (size_t)BATCHN * SEQ * HID;

    __shared__ float s_act[2][G7];                 // parity double-buffer
    __shared__ float s_times[SEQ];

    const int c0 = tid;                                   // cols 0..255
    const int c1 = (wave < 3) ? tid + 256 : tid;          // cols 256..447

    // Two h-part weight columns per thread, packed as float2 (128 VGPRs).
    float2 wh[HID];
    if (f32) {
        const float* W = (const float*)W_rec;
#pragma unroll
        for (int k = 0; k < HID; ++k) {
            wh[k].x = W[(size_t)(NF + k) * G7 + c0];
            wh[k].y = W[(size_t)(NF + k) * G7 + c1];
        }
    } else {
        const bf16* W = (const bf16*)W_rec;
#pragma unroll
        for (int k = 0; k < HID; ++k) {
            wh[k].x = b2f(W[(size_t)(NF + k) * G7 + c0]);
            wh[k].y = b2f(W[(size_t)(NF + k) * G7 + c1]);
        }
    }

    for (int i = tid; i < SEQ; i += REC_T)
        s_times[i] = ldin(batch, (bT + i) * CH, f32);

    float h_reg = 0.0f, c_decay = 0.0f, c_bar = 0.0f;     // per lane j

    // xz register pipeline, 2 steps deep (covers HBM/L3 latency).
    float xa0 = xz[bT * G7 + c0];
    float xb0 = xz[bT * G7 + c1];
    float xa1 = xz[(bT + 1) * G7 + c0];
    float xb1 = xz[(bT + 1) * G7 + c1];
    __syncthreads();

    for (int t = 0; t < SEQ; ++t) {
        // Prefetch xz for t+2 (used two iterations from now).
        float xa2 = 0.0f, xb2 = 0.0f;
        if (t + 2 < SEQ) {
            xa2 = xz[(bT + t + 2) * G7 + c0];
            xb2 = xz[(bT + t + 2) * G7 + c1];
        }

        // ---- Phase B: z = xz + dot(h, wh); h broadcast via readlane.
        float a0x = 0.f, a1x = 0.f, a2x = 0.f, a3x = 0.f;
        float a0y = 0.f, a1y = 0.f, a2y = 0.f, a3y = 0.f;
#pragma unroll
        for (int k = 0; k < HID; k += 4) {
            const float h0 = rl(h_reg, k + 0);
            const float h1 = rl(h_reg, k + 1);
            const float h2 = rl(h_reg, k + 2);
            const float h3 = rl(h_reg, k + 3);
            a0x = fmaf(h0, wh[k + 0].x, a0x); a0y = fmaf(h0, wh[k + 0].y, a0y);
            a1x = fmaf(h1, wh[k + 1].x, a1x); a1y = fmaf(h1, wh[k + 1].y, a1y);
            a2x = fmaf(h2, wh[k + 2].x, a2x); a2y = fmaf(h2, wh[k + 2].y, a2y);
            a3x = fmaf(h3, wh[k + 3].x, a3x); a3y = fmaf(h3, wh[k + 3].y, a3y);
        }
        const float z0 = xa0 + ((a0x + a1x) + (a2x + a3x));
        const float z1 = xb0 + ((a0y + a1y) + (a2y + a3y));

        // g0 = wave: 0:i 1:f 2:g(tanh) 3:o ; g1 = wave+4: 4:ibar 5:fbar 6:delta
        const float act0 = (wave == 2) ? tanh_f(z0) : sigmoid_f(z0);
        const float act1 = (wave == 2) ? softplus_f(z1) : sigmoid_f(z1);

        const int p = t & 1;
        s_act[p][c0] = act0;
        if (wave < 3) s_act[p][c1] = act1;

        // Raw barrier: only LDS must be visible; stores/loads keep flying.
        asm volatile("s_waitcnt lgkmcnt(0)" ::: "memory");
        __builtin_amdgcn_s_barrier();
        __builtin_amdgcn_sched_barrier(0);

        // ---- Phase C: replicated in every wave for hidden unit j = lane.
        const float ig = s_act[p][lane];
        const float fg = s_act[p][HID + lane];
        const float gg = s_act[p][2 * HID + lane];
        const float og = s_act[p][3 * HID + lane];
        const float ib = s_act[p][4 * HID + lane];
        const float fb = s_act[p][5 * HID + lane];
        const float dl = s_act[p][6 * HID + lane];
        const float c   = fg * c_decay + ig * gg;
        const float cbn = fb * c_bar + ib * gg;
        float dt = (t + 1 < SEQ) ? (s_times[t + 1] - s_times[t]) : 0.0f;
        dt = fmaxf(dt, 0.0f);
        const float cd = cbn + (c - cbn) * __expf(-dl * dt);
        const float h  = og * tanh_f(cd);
        c_decay = cd;
        c_bar   = cbn;
        h_reg   = h;

        // Fire-and-forget stores (no barrier drain anymore).
        const size_t idx = (bT + t) * HID + lane;
        if (wave == 0)      out_c[idx]  = c;
        else if (wave == 1) out_cb[idx] = cbn;
        else if (wave == 2) h_ws[idx]   = h;
        else                { out_o[idx] = og; out_dl[idx] = dl; }

        xa0 = xa1; xb0 = xb1; xa1 = xa2; xb1 = xb2;
    }
}

// ---------------- fallback recurrent kernel (R5 structure, no xz ws) --------
__global__ __launch_bounds__(G7, 2) void ctlstm_rec(
    const void* __restrict__ batch, const void* __restrict__ W_rec,
    const void* __restrict__ b_rec, float* __restrict__ out,
    float* __restrict__ h_ws, int use_ws, const int* __restrict__ flag)
{
    const bool f32 = flag ? (*flag != 0) : true;
    const int tid = threadIdx.x;
    const int b   = blockIdx.x;
    const size_t bT = (size_t)b * SEQ;

    float* out_o  = out;
    float* out_c  = out + (size_t)BATCHN * SEQ * HID;
    float* out_cb = out + 2 * (size_t)BATCHN * SEQ * HID;
    float* out_dl = out + 3 * (size_t)BATCHN * SEQ * HID;

    __shared__ __align__(16) float s_in[DIN];
    __shared__ float s_act[G7];
    __shared__ float s_times[SEQ];

    float wcol[DIN];
    if (f32) {
        const float* W = (const float*)W_rec;
#pragma unroll
        for (int k = 0; k < DIN; ++k) wcol[k] = W[(size_t)k * G7 + tid];
    } else {
        const bf16* W = (const bf16*)W_rec;
#pragma unroll
        for (int k = 0; k < DIN; ++k) wcol[k] = b2f(W[(size_t)k * G7 + tid]);
    }
    const float bias = ldin(b_rec, tid, f32);

    for (int i = tid; i < SEQ; i += G7)
        s_times[i] = ldin(batch, (bT + i) * CH, f32);

    if (tid >= NF && tid < DIN) s_in[tid] = 0.0f;
    float c_decay = 0.0f, c_bar = 0.0f;

    float xpref = 0.0f;
    if (tid < NF) xpref = ldin(batch, bT * CH + 1 + tid, f32);
    __syncthreads();

    const int gate = tid >> 6;
    const int lane = tid & 63;

    for (int t = 0; t < SEQ; ++t) {
        if (tid < NF) s_in[tid] = xpref;
        __syncthreads();

        const float4* sv = (const float4*)s_in;
        float a0 = 0.f, a1 = 0.f, a2 = 0.f, a3 = 0.f;
#pragma unroll
        for (int k4 = 0; k4 < DIN / 4; ++k4) {
            float4 v = sv[k4];
            a0 = fmaf(v.x, wcol[4 * k4 + 0], a0);
            a1 = fmaf(v.y, wcol[4 * k4 + 1], a1);
            a2 = fmaf(v.z, wcol[4 * k4 + 2], a2);
            a3 = fmaf(v.w, wcol[4 * k4 + 3], a3);
        }
        const float z = bias + ((a0 + a1) + (a2 + a3));

        float act;
        if (gate == 2)      act = tanh_f(z);
        else if (gate == 6) act = softplus_f(z);
        else                act = sigmoid_f(z);
        s_act[tid] = act;

        const size_t oidx = (bT + t) * HID + lane;
        if (gate == 3) out_o[oidx]  = act;
        if (gate == 6) out_dl[oidx] = act;
        __syncthreads();

        if (tid < HID) {
            const float ig = s_act[tid];
            const float fg = s_act[HID + tid];
            const float gg = s_act[2 * HID + tid];
            const float og = s_act[3 * HID + tid];
            const float ib = s_act[4 * HID + tid];
            const float fb = s_act[5 * HID + tid];
            const float dl = s_act[6 * HID + tid];
            const float c  = fg * c_decay + ig * gg;
            const float cb = fb * c_bar + ib * gg;
            float dt = (t + 1 < SEQ) ? (s_times[t + 1] - s_times[t]) : 0.0f;
            dt = fmaxf(dt, 0.0f);
            const float cd = cb + (c - cb) * __expf(-dl * dt);
            const float h  = og * tanh_f(cd);
            c_decay = cd;
            c_bar   = cb;
            s_in[NF + tid] = h;
            const size_t idx = (bT + t) * HID + tid;
            out_c[idx]  = c;
            out_cb[idx] = cb;
            if (use_ws) h_ws[idx] = h;
        }
        if (tid < NF && t + 1 < SEQ)
            xpref = ldin(batch, (bT + t + 1) * CH + 1 + tid, f32);
    }
}

// ---------------- intensity head ----------------
__global__ __launch_bounds__(256) void intensity_ws(
    const float* __restrict__ h_ws, const void* __restrict__ W_int,
    const void* __restrict__ b_int, float* __restrict__ out_int,
    const int* __restrict__ flag)
{
    const bool f32 = flag ? (*flag != 0) : true;
    __shared__ float s_w[HID * NF];
    __shared__ float s_b[NF];
    const int tx = threadIdx.x, ty = threadIdx.y;
    const int lt = ty * 32 + tx;
    for (int k = lt; k < HID * NF; k += 256) s_w[k] = ldin(W_int, k, f32);
    if (lt < NF) s_b[lt] = ldin(b_int, lt, f32);
    __syncthreads();

    const int b = blockIdx.y;
    const int t = blockIdx.x * 8 + ty;
    if (t >= SEQ - 1) return;
    const float* hr = h_ws + ((size_t)b * SEQ + t) * HID;
    float acc = s_b[tx];
#pragma unroll
    for (int k = 0; k < HID; ++k) acc = fmaf(hr[k], s_w[k * NF + tx], acc);
    out_int[((size_t)b * (SEQ - 1) + t) * NF + tx] = softplus_f(acc);
}

__global__ __launch_bounds__(256) void intensity_rec(
    const void* __restrict__ batch, const float* __restrict__ out,
    const void* __restrict__ W_int, const void* __restrict__ b_int,
    float* __restrict__ out_int, const int* __restrict__ flag)
{
    const bool f32 = flag ? (*flag != 0) : true;
    __shared__ float s_w[HID * NF];
    __shared__ float s_b[NF];
    __shared__ float s_h[8][HID];
    const int tx = threadIdx.x, ty = threadIdx.y;
    const int lt = ty * 32 + tx;
    for (int k = lt; k < HID * NF; k += 256) s_w[k] = ldin(W_int, k, f32);
    if (lt < NF) s_b[lt] = ldin(b_int, lt, f32);

    const int b  = blockIdx.y;
    const int t0 = blockIdx.x * 8;
    const float* out_o  = out;
    const float* out_c  = out + (size_t)BATCHN * SEQ * HID;
    const float* out_cb = out + 2 * (size_t)BATCHN * SEQ * HID;
    const float* out_dl = out + 3 * (size_t)BATCHN * SEQ * HID;

#pragma unroll
    for (int r = 0; r < 2; ++r) {
        const int flat = lt + r * 256;
        const int row  = flat >> 6;
        const int k    = flat & 63;
        const int t    = t0 + row;
        if (t < SEQ - 1) {
            const size_t idx = ((size_t)b * SEQ + t) * HID + k;
            const float og = out_o[idx];
            const float c  = out_c[idx];
            const float cb = out_cb[idx];
            const float dl = out_dl[idx];
            const float t_a = ldin(batch, ((size_t)b * SEQ + t) * CH, f32);
            const float t_b = ldin(batch, ((size_t)b * SEQ + t + 1) * CH, f32);
            const float dt = fmaxf(t_b - t_a, 0.0f);
            const float cd = cb + (c - cb) * __expf(-dl * dt);
            s_h[row][k] = og * tanh_f(cd);
        }
    }
    __syncthreads();
    const int t = t0 + ty;
    if (t >= SEQ - 1) return;
    float acc = s_b[tx];
#pragma unroll
    for (int k = 0; k < HID; ++k) acc = fmaf(s_h[ty][k], s_w[k * NF + tx], acc);
    out_int[((size_t)b * (SEQ - 1) + t) * NF + tx] = softplus_f(acc);
}

extern "C" void kernel_launch(void* const* d_in, const int* in_sizes, int n_in,
                              void* d_out, int out_size, void* d_ws, size_t ws_size,
                              hipStream_t stream) {
    const void* batch = d_in[0];
    const void* W_rec = d_in[1];
    const void* b_rec = d_in[2];
    const void* W_int = d_in[3];
    const void* b_int = d_in[4];
    float* out = (float*)d_out;

    // ws layout: [0,256) flag | [256, 256+hb) fp32 h | [256+hb, ...) xz buffer
    const size_t hb  = (size_t)BATCHN * SEQ * HID * sizeof(float);   // 33.5 MB
    const size_t xzb = (size_t)BATCHN * SEQ * G7  * sizeof(float);   // 235 MB
    int*   flag = (ws_size >= 4) ? (int*)d_ws : nullptr;
    float* h_ws = (float*)((char*)d_ws + 256);
    float* xz   = (float*)((char*)d_ws + 256 + hb);
    const int have_h  = (ws_size >= 256 + hb) ? 1 : 0;          // launch-constant
    const int have_xz = (ws_size >= 256 + hb + xzb) ? 1 : 0;    // launch-constant

    if (flag) detect_dtype<<<1, 64, 0, stream>>>(batch, flag);

    float* out_int = out + 4 * (size_t)BATCHN * SEQ * HID;

    if (have_xz) {
        xproj_gemm<<<(BATCHN * SEQ) / 64, G7, 0, stream>>>(batch, W_rec, b_rec, xz, flag);
        ctlstm_rec_xz4<<<BATCHN, REC_T, 0, stream>>>(batch, W_rec, xz, out, h_ws, flag);
        intensity_ws<<<dim3((SEQ - 1 + 7) / 8, BATCHN), dim3(32, 8), 0, stream>>>(
            h_ws, W_int, b_int, out_int, flag);
    } else if (have_h) {
        ctlstm_rec<<<BATCHN, G7, 0, stream>>>(batch, W_rec, b_rec, out, h_ws, 1, flag);
        intensity_ws<<<dim3((SEQ - 1 + 7) / 8, BATCHN), dim3(32, 8), 0, stream>>>(
            h_ws, W_int, b_int, out_int, flag);
    } else {
        ctlstm_rec<<<BATCHN, G7, 0, stream>>>(batch, W_rec, b_rec, out, h_ws, 0, flag);
        intensity_rec<<<dim3((SEQ - 1 + 7) / 8, BATCHN), dim3(32, 8), 0, stream>>>(
            batch, out, W_int, b_int, out_int, flag);
    }
}